// Round 13
// baseline (214.627 us; speedup 1.0000x reference)
//
#include <hip/hip_runtime.h>

#define HDIM 64
#define F1 256
#define F3 192
#define FH 128

typedef unsigned short u16;
typedef __attribute__((ext_vector_type(8))) short short8;
typedef __attribute__((ext_vector_type(4))) float f32x4;
typedef __attribute__((ext_vector_type(2))) unsigned int uint2v;  // 8B

// fp32 -> bf16(hi) + bf16(lo), both RNE
__device__ __forceinline__ void split2(float v, u16& h, u16& l) {
  unsigned u = __float_as_uint(v);
  unsigned r = u + 0x7FFFu + ((u >> 16) & 1u);
  h = (u16)(r >> 16);
  float fh = __uint_as_float(((unsigned)h) << 16);
  float res = v - fh;
  unsigned u2 = __float_as_uint(res);
  unsigned r2 = u2 + 0x7FFFu + ((u2 >> 16) & 1u);
  l = (u16)(r2 >> 16);
}

__device__ __forceinline__ u16 bf16r(float v) {
  unsigned u = __float_as_uint(v);
  return (u16)((u + 0x7FFFu + ((u >> 16) & 1u)) >> 16);
}
__device__ __forceinline__ float bf2f(u16 h) {
  return __uint_as_float(((unsigned)h) << 16);
}

// ------------- 2-kernel scan; MODE 0 also zeroes counts/pooled/nact -------------
template <int MODE>
__global__ __launch_bounds__(256) void scan_p1(const int* __restrict__ in,
                                               int* __restrict__ blocksum,
                                               float* __restrict__ dinv,
                                               int* __restrict__ counts,
                                               float* __restrict__ pooled,
                                               int* __restrict__ nact, int N) {
  __shared__ int wsum[4];
  if (MODE == 0) {
    int gi = blockIdx.x * blockDim.x + threadIdx.x;
    int gstride = gridDim.x * blockDim.x;
    for (int j = gi; j < N; j += gstride) counts[j] = 0;
    if (gi < F3) pooled[gi] = 0.0f;
    if (gi == 0) *nact = 0;
  }
  int base = blockIdx.x * 1024 + threadIdx.x * 4;
  int s = 0;
#pragma unroll
  for (int j = 0; j < 4; ++j) {
    int i = base + j;
    if (i < N) {
      int v = in[i];
      if (MODE == 0) s += (v == 0 ? 1 : 0);
      else {
        s += v;
        dinv[i] = rsqrtf(1.0f + (float)v);
      }
    }
  }
#pragma unroll
  for (int off = 32; off; off >>= 1) s += __shfl_xor(s, off);
  if ((threadIdx.x & 63) == 0) wsum[threadIdx.x >> 6] = s;
  __syncthreads();
  if (threadIdx.x == 0)
    blocksum[blockIdx.x] = wsum[0] + wsum[1] + wsum[2] + wsum[3];
}

// p3 computes its own block offset from raw blocksum (G <= 64 blocks, cheap).
template <int MODE>
__global__ __launch_bounds__(256) void scan_p3(const int* __restrict__ in,
                                               const int* __restrict__ blocksum,
                                               int* __restrict__ out0,
                                               int* __restrict__ out1,
                                               int* __restrict__ NmInt,
                                               float* __restrict__ mcnt, int N) {
  __shared__ int wsum[4];
  const int tid = threadIdx.x;
  int base = blockIdx.x * 1024 + tid * 4;
  int c[4];
  int tsum = 0;
#pragma unroll
  for (int j = 0; j < 4; ++j) {
    int i = base + j;
    c[j] = (i < N) ? ((MODE == 0) ? (in[i] == 0 ? 1 : 0) : in[i]) : 0;
    tsum += c[j];
  }
  int v = tsum;
#pragma unroll
  for (int off = 1; off < 64; off <<= 1) {
    int t = __shfl_up(v, off);
    if ((tid & 63) >= off) v += t;
  }
  int wexcl = v - tsum;
  if ((tid & 63) == 63) wsum[tid >> 6] = v;
  __shared__ int boff;
  if (tid == 0) {
    int b = 0;
    for (int j = 0; j < blockIdx.x; ++j) b += blocksum[j];
    boff = b;
  }
  __syncthreads();
  int wbase = 0;
  int wv = tid >> 6;
#pragma unroll
  for (int j = 0; j < 4; ++j)
    if (j < wv) wbase += wsum[j];
  int off0 = boff + wbase + wexcl;
#pragma unroll
  for (int j = 0; j < 4; ++j) {
    int i = base + j;
    if (i < N) {
      if (MODE == 0) {
        out0[i] = off0;
        if (c[j]) out1[off0] = i;
        off0 += c[j];
        if (i == N - 1) { *NmInt = off0; *mcnt = (float)off0; }
      } else {
        out0[i] = off0;
        out1[i] = off0;
        off0 += c[j];
        if (i == N - 1) out0[N] = off0;
      }
    }
  }
}

// ---- single full-edge scan: append active (ns,nd) (1 atomic/block) + in-degree ----
__global__ __launch_bounds__(256) void compact_edges_kernel(
    const int* __restrict__ ei, const int* __restrict__ nt,
    const int* __restrict__ newidx, int* __restrict__ nact,
    int2* __restrict__ ae, int* __restrict__ counts, int E) {
  __shared__ int wbase[4];
  const int tid = threadIdx.x;
  const int lane = tid & 63, wv = tid >> 6;
  const int e0 = blockIdx.x * 1024;
  int s[4], d[4];
  bool act[4];
  int cnt = 0;
#pragma unroll
  for (int j = 0; j < 4; ++j) {
    int e = e0 + j * 256 + tid;
    if (e < E) {
      s[j] = ei[e];
      d[j] = ei[E + e];
      act[j] = (nt[s[j]] == 0 && nt[d[j]] == 0);
    } else {
      act[j] = false;
    }
    cnt += act[j] ? 1 : 0;
  }
  int v = cnt;
#pragma unroll
  for (int off = 1; off < 64; off <<= 1) {
    int t = __shfl_up(v, off);
    if (lane >= off) v += t;
  }
  int wexcl = v - cnt;
  if (lane == 63) wbase[wv] = v;
  __syncthreads();
  if (tid == 0) {
    int t0 = wbase[0], t1 = wbase[1], t2 = wbase[2], t3 = wbase[3];
    int b = atomicAdd(nact, t0 + t1 + t2 + t3);
    wbase[0] = b;
    wbase[1] = b + t0;
    wbase[2] = b + t0 + t1;
    wbase[3] = b + t0 + t1 + t2;
  }
  __syncthreads();
  int pos = wbase[wv] + wexcl;
#pragma unroll
  for (int j = 0; j < 4; ++j) {
    if (act[j]) {
      int ns = newidx[s[j]], nd = newidx[d[j]];
      ae[pos] = make_int2(ns, nd);
      atomicAdd(&counts[nd], 1);
      ++pos;
    }
  }
}

// ---- CSR fill over active list ----
__global__ __launch_bounds__(256) void fill2_kernel(const int2* __restrict__ ae,
                                                    const int* __restrict__ nactp,
                                                    const float* __restrict__ dinv,
                                                    int* __restrict__ fill,
                                                    int* __restrict__ csr_src,
                                                    float* __restrict__ csr_w) {
  int n = *nactp;
  int i = blockIdx.x * blockDim.x + threadIdx.x;
  int stride = gridDim.x * blockDim.x;
  for (int e = i; e < n; e += stride) {
    int2 p = ae[e];
    int pos = atomicAdd(&fill[p.y], 1);
    csr_src[pos] = p.x;
    csr_w[pos] = dinv[p.x] * dinv[p.y];
  }
}

// ---- prep: weight splits (blocks 0..543) + z0c bf16 compacted emb (rest) ----
__global__ __launch_bounds__(256) void prep_kernel(
    const float* __restrict__ W1, const float* __restrict__ W2,
    const float* __restrict__ W3, const float* __restrict__ Wh1t,
    u16* __restrict__ T1h, u16* __restrict__ T1l,
    u16* __restrict__ T2h, u16* __restrict__ T2l,
    u16* __restrict__ T3h, u16* __restrict__ T3l,
    u16* __restrict__ Hh, u16* __restrict__ Hl,
    const int* __restrict__ nodelist, const float* __restrict__ emb,
    u16* __restrict__ z0c, const int* __restrict__ NmPtr) {
  const int WB = 544;  // 139264 / 256
  if (blockIdx.x < WB) {
    int i = blockIdx.x * 256 + threadIdx.x;
    const float* W; u16 *Th, *Tl; int FIN, FOUT, idx;
    if (i < 16384) { W = W1; Th = T1h; Tl = T1l; FIN = 64; FOUT = 256; idx = i; }
    else if (i < 81920) { W = W2; Th = T2h; Tl = T2l; FIN = 256; FOUT = 256; idx = i - 16384; }
    else if (i < 131072) { W = W3; Th = T3h; Tl = T3l; FIN = 256; FOUT = 192; idx = i - 81920; }
    else if (i < 139264) { W = Wh1t; Th = Hh; Tl = Hl; FIN = 64; FOUT = 128; idx = i - 131072; }
    else return;
    int k = idx / FOUT, c = idx % FOUT;
    u16 h, l;
    split2(W[idx], h, l);
    Th[(size_t)c * FIN + k] = h;
    Tl[(size_t)c * FIN + k] = l;
  } else {
    int Nm = *NmPtr;
    int i = (blockIdx.x - WB) * 256 + threadIdx.x;
    int stride = (gridDim.x - WB) * 256;
    int total = Nm * (HDIM / 4);
    for (int j = i; j < total; j += stride) {
      int row = j >> 4;
      int c = (j & 15) * 4;
      int xr = nodelist[row];
      float4 v = *(const float4*)&emb[(size_t)xr * HDIM + c];
      uint2v o;
      o[0] = (unsigned)bf16r(v.x) | ((unsigned)bf16r(v.y) << 16);
      o[1] = (unsigned)bf16r(v.z) | ((unsigned)bf16r(v.w) << 16);
      *(uint2v*)&z0c[(size_t)row * HDIM + c] = o;
    }
  }
}

// ---- input-side aggregation, 64-dim bf16 ----
__global__ __launch_bounds__(256) void agg64_kernel(
    const u16* __restrict__ z0c, const int* __restrict__ rowstart,
    const int* __restrict__ csr_src, const float* __restrict__ csr_w,
    const float* __restrict__ dinv,
    u16* __restrict__ Ab, const int* __restrict__ NmPtr) {
  const int Nm = *NmPtr;
  const int lane = threadIdx.x & 63;
  const int wid = (int)((blockIdx.x * blockDim.x + threadIdx.x) >> 6);
  const int nw = (int)((gridDim.x * blockDim.x) >> 6);
  for (int r = wid; r < Nm; r += nw) {
    const int e0 = rowstart[r];
    const int e1 = rowstart[r + 1];
    float di = dinv[r];
    float acc = di * di * bf2f(z0c[(size_t)r * HDIM + lane]);
    for (int eb = e0; eb < e1; eb += 8) {
      int s[8]; float w[8];
#pragma unroll
      for (int u = 0; u < 8; ++u) {
        int idx = eb + u;
        bool ok = idx < e1;
        s[u] = ok ? csr_src[idx] : r;
        w[u] = ok ? csr_w[idx] : 0.f;
      }
      float v[8];
#pragma unroll
      for (int u = 0; u < 8; ++u) v[u] = bf2f(z0c[(size_t)s[u] * HDIM + lane]);
#pragma unroll
      for (int u = 0; u < 8; ++u) acc += w[u] * v[u];
    }
    Ab[(size_t)r * HDIM + lane] = bf16r(acc);
  }
}

// ---- input-side aggregation, 256-dim bf16 ----
__global__ __launch_bounds__(256) void agg256_kernel(
    const u16* __restrict__ Z, const int* __restrict__ rowstart,
    const int* __restrict__ csr_src, const float* __restrict__ csr_w,
    const float* __restrict__ dinv,
    u16* __restrict__ Ab, const int* __restrict__ NmPtr) {
  const int Nm = *NmPtr;
  const int lane = threadIdx.x & 63;
  const int wid = (int)((blockIdx.x * blockDim.x + threadIdx.x) >> 6);
  const int nw = (int)((gridDim.x * blockDim.x) >> 6);
  for (int r = wid; r < Nm; r += nw) {
    const int e0 = rowstart[r];
    const int e1 = rowstart[r + 1];
    float di = dinv[r];
    float sn = di * di;
    uint2v sp = *(const uint2v*)&Z[(size_t)r * F1 + 4 * lane];
    float a0 = sn * __uint_as_float(sp[0] << 16);
    float a1 = sn * __uint_as_float(sp[0] & 0xFFFF0000u);
    float a2 = sn * __uint_as_float(sp[1] << 16);
    float a3 = sn * __uint_as_float(sp[1] & 0xFFFF0000u);
    for (int eb = e0; eb < e1; eb += 8) {
      int s[8]; float w[8];
#pragma unroll
      for (int u = 0; u < 8; ++u) {
        int idx = eb + u;
        bool ok = idx < e1;
        s[u] = ok ? csr_src[idx] : r;
        w[u] = ok ? csr_w[idx] : 0.f;
      }
      uint2v pv[8];
#pragma unroll
      for (int u = 0; u < 8; ++u) pv[u] = *(const uint2v*)&Z[(size_t)s[u] * F1 + 4 * lane];
#pragma unroll
      for (int u = 0; u < 8; ++u) {
        a0 += w[u] * __uint_as_float(pv[u][0] << 16);
        a1 += w[u] * __uint_as_float(pv[u][0] & 0xFFFF0000u);
        a2 += w[u] * __uint_as_float(pv[u][1] << 16);
        a3 += w[u] * __uint_as_float(pv[u][1] & 0xFFFF0000u);
      }
    }
    uint2v o;
    o[0] = (unsigned)bf16r(a0) | ((unsigned)bf16r(a1) << 16);
    o[1] = (unsigned)bf16r(a2) | ((unsigned)bf16r(a3) << 16);
    *(uint2v*)&Ab[(size_t)r * F1 + 4 * lane] = o;
  }
}

// ------- MFMA GEMM: A single bf16, W split hi/lo. Tile = ROWS x COLS.
// Wave handles MI*16 rows (MI = ROWS/64). MODE 1: store bf16 relu. MODE 2: pool.
template <int FIN, int FOUT, int ROWS, int COLS, int MODE>
__global__ __launch_bounds__(256) void gemm_kernel(const u16* __restrict__ A,
                                                   const u16* __restrict__ Wh,
                                                   const u16* __restrict__ Wl,
                                                   const float* __restrict__ bias,
                                                   u16* __restrict__ Out,
                                                   float* __restrict__ pooled,
                                                   const int* __restrict__ NmPtr) {
  const int NI = COLS / 16;
  const int MI = ROWS / 64;   // 16-row groups per wave
  const int WR = MI * 16;     // rows per wave
  const int Nm = *NmPtr;
  const int r0 = blockIdx.x * ROWS, c0 = blockIdx.y * COLS;
  if (r0 >= Nm) return;
  __shared__ u16 AH[8 * ROWS * 8];
  __shared__ u16 WH[8 * COLS * 8], WL[8 * COLS * 8];
  const int tid = threadIdx.x;
  const int lane = tid & 63, w = tid >> 6;
  const int l15 = lane & 15, l4 = lane >> 4;
  f32x4 acc[MI][NI] = {};

  for (int k0 = 0; k0 < FIN; k0 += 64) {
#pragma unroll
    for (int p = 0; p < ROWS / 32; ++p) {
      int e = p * 2048 + tid * 8;
      int r = e >> 6, ke = e & 63;
      int g0 = ke >> 2;
      int h = (g0 >> 2) & 1;
      int gp = (g0 & 3) | ((g0 >> 3) << 2);
      uint2v v0 = {0, 0}, v1 = {0, 0};
      if (r0 + r < Nm) {
        size_t gbase = (size_t)(r0 + r) * FIN + k0 + ke;
        v0 = *(const uint2v*)&A[gbase];
        v1 = *(const uint2v*)&A[gbase + 4];
      }
      *(uint2v*)&AH[((gp * ROWS + r) * 8) + h * 4] = v0;
      *(uint2v*)&AH[(((gp + 1) * ROWS + r) * 8) + h * 4] = v1;
    }
#pragma unroll
    for (int p = 0; p < COLS / 32; ++p) {
      int e = p * 2048 + tid * 8;
      int c = e >> 6, ke = e & 63;
      int g0 = ke >> 2;
      int h = (g0 >> 2) & 1;
      int gp = (g0 & 3) | ((g0 >> 3) << 2);
      size_t gbase = (size_t)(c0 + c) * FIN + k0 + ke;
      uint2v vh0 = *(const uint2v*)&Wh[gbase];
      uint2v vh1 = *(const uint2v*)&Wh[gbase + 4];
      uint2v vl0 = *(const uint2v*)&Wl[gbase];
      uint2v vl1 = *(const uint2v*)&Wl[gbase + 4];
      *(uint2v*)&WH[((gp * COLS + c) * 8) + h * 4] = vh0;
      *(uint2v*)&WH[(((gp + 1) * COLS + c) * 8) + h * 4] = vh1;
      *(uint2v*)&WL[((gp * COLS + c) * 8) + h * 4] = vl0;
      *(uint2v*)&WL[(((gp + 1) * COLS + c) * 8) + h * 4] = vl1;
    }
    __syncthreads();
#pragma unroll
    for (int ko = 0; ko < 2; ++ko) {
      const int gb = ko * 4 + l4;
      short8 af[MI];
#pragma unroll
      for (int mi = 0; mi < MI; ++mi)
        af[mi] = *(const short8*)&AH[(gb * ROWS + (w * WR + mi * 16 + l15)) * 8];
#pragma unroll
      for (int ni = 0; ni < NI; ++ni) {
        int slot = gb * COLS + (ni * 16 + l15);
        short8 wh = *(const short8*)&WH[slot * 8];
        short8 wl = *(const short8*)&WL[slot * 8];
#pragma unroll
        for (int mi = 0; mi < MI; ++mi) {
          acc[mi][ni] = __builtin_amdgcn_mfma_f32_16x16x32_bf16(af[mi], wh, acc[mi][ni], 0, 0, 0);
          acc[mi][ni] = __builtin_amdgcn_mfma_f32_16x16x32_bf16(af[mi], wl, acc[mi][ni], 0, 0, 0);
        }
      }
    }
    __syncthreads();
  }

  float bb[NI];
#pragma unroll
  for (int ni = 0; ni < NI; ++ni) bb[ni] = bias[c0 + ni * 16 + l15];

  if (MODE == 1) {
#pragma unroll
    for (int mi = 0; mi < MI; ++mi)
#pragma unroll
      for (int ni = 0; ni < NI; ++ni)
#pragma unroll
        for (int j = 0; j < 4; ++j) {
          int row = r0 + w * WR + mi * 16 + l4 * 4 + j;
          if (row < Nm)
            Out[(size_t)row * FOUT + c0 + ni * 16 + l15] =
                bf16r(fmaxf(acc[mi][ni][j] + bb[ni], 0.f));
        }
  } else {
    __shared__ float wred[4][COLS];
    float part[NI];
#pragma unroll
    for (int ni = 0; ni < NI; ++ni) part[ni] = 0.f;
#pragma unroll
    for (int mi = 0; mi < MI; ++mi)
#pragma unroll
      for (int ni = 0; ni < NI; ++ni)
#pragma unroll
        for (int j = 0; j < 4; ++j) {
          int row = r0 + w * WR + mi * 16 + l4 * 4 + j;
          if (row < Nm) part[ni] += fmaxf(acc[mi][ni][j] + bb[ni], 0.f);
        }
#pragma unroll
    for (int ni = 0; ni < NI; ++ni) {
      part[ni] += __shfl_xor(part[ni], 16);
      part[ni] += __shfl_xor(part[ni], 32);
    }
    if (l4 == 0)
#pragma unroll
      for (int ni = 0; ni < NI; ++ni) wred[w][ni * 16 + l15] = part[ni];
    __syncthreads();
    if (tid < COLS) {
      float s = wred[0][tid] + wred[1][tid] + wred[2][tid] + wred[3][tid];
      atomicAdd(&pooled[c0 + tid], s);
    }
  }
}

// ---- MFMA head, 64-row tiles, fused phead/gw/hcst prologue ----
__global__ __launch_bounds__(256) void head_mfma_kernel(
    const int* __restrict__ x, const float* __restrict__ emb,
    const u16* __restrict__ Hh, const u16* __restrict__ Hl,
    const float* __restrict__ pooled, const float* __restrict__ mcnt,
    const float* __restrict__ Wh1, const float* __restrict__ bh1,
    const float* __restrict__ gamma, const float* __restrict__ beta,
    const float* __restrict__ Wh2, const float* __restrict__ bh2,
    float* __restrict__ out, int N) {
  const int tid = threadIdx.x;
  const int lane = tid & 63, w = tid >> 6;
  const int l15 = lane & 15, l4 = lane >> 4;
  const int r0 = blockIdx.x * 64;

  __shared__ float sph[FH], sgw[FH];
  __shared__ float shc;
  if (tid < FH) {
    float inv = 1.0f / *mcnt;
    float acc = bh1[tid];
    for (int k = 0; k < F3; ++k) acc += pooled[k] * inv * Wh1[k * FH + tid];
    sph[tid] = acc;
    const float bninv = 1.0f / sqrtf(1.0f + 1e-5f);
    sgw[tid] = gamma[tid] * bninv * Wh2[tid];
  }
  if (tid == 0) {
    float s = bh2[0];
    for (int i = 0; i < FH; ++i) s += beta[i] * Wh2[i];
    shc = s;
  }
  __syncthreads();

  f32x4 acc[8] = {};
  const short8 zfrag = {};

#pragma unroll
  for (int ko = 0; ko < 2; ++ko) {
    const int kb = 32 * ko + 4 * l4;
    short8 bh[8], bl[8], ah, al;
#pragma unroll
    for (int ni = 0; ni < 8; ++ni) {
      int col = ni * 16 + l15;
      const u16* p = &Hh[col * 64 + kb];
      ((uint2v*)&bh[ni])[0] = *(const uint2v*)p;
      ((uint2v*)&bh[ni])[1] = *(const uint2v*)(p + 16);
      const u16* q = &Hl[col * 64 + kb];
      ((uint2v*)&bl[ni])[0] = *(const uint2v*)q;
      ((uint2v*)&bl[ni])[1] = *(const uint2v*)(q + 16);
    }
    {
      int row = r0 + w * 16 + l15;
      if (row < N) {
        int xr = x[row];
        const float* pr = &emb[(size_t)xr * HDIM + kb];
        float4 f0 = *(const float4*)pr;
        float4 f1 = *(const float4*)(pr + 16);
        u16 hh[8], ll[8];
        split2(f0.x, hh[0], ll[0]); split2(f0.y, hh[1], ll[1]);
        split2(f0.z, hh[2], ll[2]); split2(f0.w, hh[3], ll[3]);
        split2(f1.x, hh[4], ll[4]); split2(f1.y, hh[5], ll[5]);
        split2(f1.z, hh[6], ll[6]); split2(f1.w, hh[7], ll[7]);
        short8 a, b;
#pragma unroll
        for (int j = 0; j < 8; ++j) { a[j] = (short)hh[j]; b[j] = (short)ll[j]; }
        ah = a;
        al = b;
      } else {
        ah = zfrag;
        al = zfrag;
      }
    }
#pragma unroll
    for (int ni = 0; ni < 8; ++ni) {
      acc[ni] = __builtin_amdgcn_mfma_f32_16x16x32_bf16(ah, bh[ni], acc[ni], 0, 0, 0);
      acc[ni] = __builtin_amdgcn_mfma_f32_16x16x32_bf16(ah, bl[ni], acc[ni], 0, 0, 0);
      acc[ni] = __builtin_amdgcn_mfma_f32_16x16x32_bf16(al, bh[ni], acc[ni], 0, 0, 0);
    }
  }

  const float hc = shc;
  float ph[8], g[8];
#pragma unroll
  for (int ni = 0; ni < 8; ++ni) {
    int col = ni * 16 + l15;
    ph[ni] = sph[col];
    g[ni] = sgw[col];
  }
#pragma unroll
  for (int j = 0; j < 4; ++j) {
    float s = 0.f;
#pragma unroll
    for (int ni = 0; ni < 8; ++ni)
      s += fmaxf(acc[ni][j] + ph[ni], 0.f) * g[ni];
#pragma unroll
    for (int off = 1; off < 16; off <<= 1) s += __shfl_xor(s, off);
    int row = r0 + w * 16 + l4 * 4 + j;
    if (l15 == 0 && row < N) out[row] = s + hc;
  }
}

extern "C" void kernel_launch(void* const* d_in, const int* in_sizes, int n_in,
                              void* d_out, int out_size, void* d_ws, size_t ws_size,
                              hipStream_t stream) {
  const int N = in_sizes[0];
  const int E = in_sizes[1] / 2;

  const int* x = (const int*)d_in[0];
  const int* ei = (const int*)d_in[1];
  const int* nt = (const int*)d_in[2];
  const float* emb = (const float*)d_in[3];
  const float* W1 = (const float*)d_in[4];
  const float* b1 = (const float*)d_in[5];
  const float* W2 = (const float*)d_in[6];
  const float* b2 = (const float*)d_in[7];
  const float* W3 = (const float*)d_in[8];
  const float* b3 = (const float*)d_in[9];
  const float* Wh1 = (const float*)d_in[10];
  const float* bh1 = (const float*)d_in[11];
  const float* gamma = (const float*)d_in[12];
  const float* beta = (const float*)d_in[13];
  const float* Wh2 = (const float*)d_in[14];
  const float* bh2 = (const float*)d_in[15];
  float* out = (float*)d_out;

  // workspace layout (bf16 activations)
  u16* Ab = (u16*)d_ws;                            // N*256 u16
  u16* Bz = Ab + (size_t)N * 256;                  // N*256 u16
  u16* WTh = Bz + (size_t)N * 256;                 // 131072
  u16* WTl = WTh + 131072;                         // 131072
  u16* Hh = WTl + 131072;                          // 8192
  u16* Hl = Hh + 8192;                             // 8192
  u16* z0c = Hl + 8192;                            // N*64 u16
  float* dinv = (float*)(z0c + (size_t)N * HDIM);  // N
  float* csr_w = dinv + N;                         // E
  int* csr_src = (int*)(csr_w + E);                // E
  int2* ae = (int2*)(csr_src + E);                 // E int2
  int* counts = (int*)(ae + E);                    // N
  int* fill = counts + N;                          // N
  int* rowstart = fill + N;                        // N+1
  int* newidx = rowstart + N + 2;                  // N
  int* nodelist = newidx + N;                      // N
  int* blocksum = nodelist + N;                    // 256
  int* NmInt = blocksum + 256;                     // 1
  int* nact = NmInt + 1;                           // 1
  float* pooled = (float*)(nact + 1);              // 192
  float* mcnt = pooled + F3;                       // 1
  (void)ws_size; (void)n_in; (void)out_size;

  u16* W1Th = WTh,         * W1Tl = WTl;
  u16* W2Th = WTh + 16384, * W2Tl = WTl + 16384;
  u16* W3Th = WTh + 81920, * W3Tl = WTl + 81920;

  const int row64Blocks = (N + 63) / 64;
  const int aggBlocks = (N + 3) / 4;
  const int scanBlocks = (N + 1023) / 1024;
  const int edgeBlocks = (E + 1023) / 1024;

  // mask scan (+ zero counts/pooled/nact): newidx/nodelist/Nm/mcnt
  scan_p1<0><<<scanBlocks, 256, 0, stream>>>(nt, blocksum, nullptr, counts, pooled, nact, N);
  scan_p3<0><<<scanBlocks, 256, 0, stream>>>(nt, blocksum, newidx, nodelist, NmInt, mcnt, N);
  // single full-edge pass -> active list + in-degree counts
  compact_edges_kernel<<<edgeBlocks, 256, 0, stream>>>(ei, nt, newidx, nact, ae, counts, E);
  // counts scan (+dinv): rowstart/fill
  scan_p1<1><<<scanBlocks, 256, 0, stream>>>(counts, blocksum, dinv, nullptr, nullptr, nullptr, N);
  scan_p3<1><<<scanBlocks, 256, 0, stream>>>(counts, blocksum, rowstart, fill, NmInt, mcnt, N);
  fill2_kernel<<<512, 256, 0, stream>>>(ae, nact, dinv, fill, csr_src, csr_w);
  // weight splits + compacted bf16 emb in one launch
  prep_kernel<<<544 + 1024, 256, 0, stream>>>(
      W1, W2, W3, Wh1 + F3 * FH, W1Th, W1Tl, W2Th, W2Tl, W3Th, W3Tl, Hh, Hl,
      nodelist, emb, z0c, NmInt);

  // layer 1: 64-row tiles
  agg64_kernel<<<aggBlocks, 256, 0, stream>>>(z0c, rowstart, csr_src, csr_w, dinv, Ab, NmInt);
  gemm_kernel<HDIM, F1, 64, 128, 1><<<dim3(row64Blocks, 2), 256, 0, stream>>>(
      Ab, W1Th, W1Tl, b1, Bz, nullptr, NmInt);

  // layer 2
  agg256_kernel<<<aggBlocks, 256, 0, stream>>>(Bz, rowstart, csr_src, csr_w, dinv, Ab, NmInt);
  gemm_kernel<F1, F1, 64, 128, 1><<<dim3(row64Blocks, 2), 256, 0, stream>>>(
      Ab, W2Th, W2Tl, b2, Bz, nullptr, NmInt);

  // layer 3 (+ fused pool; z3 never stored)
  agg256_kernel<<<aggBlocks, 256, 0, stream>>>(Bz, rowstart, csr_src, csr_w, dinv, Ab, NmInt);
  gemm_kernel<F1, F3, 64, 192, 2><<<dim3(row64Blocks, 1), 256, 0, stream>>>(
      Ab, W3Th, W3Tl, b3, nullptr, pooled, NmInt);

  // head (64-row tiles, fused prologue)
  head_mfma_kernel<<<row64Blocks, 256, 0, stream>>>(
      x, emb, Hh, Hl, pooled, mcnt, Wh1, bh1, gamma, beta, Wh2, bh2, out, N);
}

// Round 14
// 195.553 us; speedup vs baseline: 1.0975x; 1.0975x over previous
//
#include <hip/hip_runtime.h>

#define HDIM 64
#define F1 256
#define F3 192
#define FH 128

typedef unsigned short u16;
typedef unsigned long long u64;
typedef __attribute__((ext_vector_type(8))) short short8;
typedef __attribute__((ext_vector_type(4))) float f32x4;
typedef __attribute__((ext_vector_type(2))) unsigned int uint2v;  // 8B

// fp32 -> bf16(hi) + bf16(lo), both RNE
__device__ __forceinline__ void split2(float v, u16& h, u16& l) {
  unsigned u = __float_as_uint(v);
  unsigned r = u + 0x7FFFu + ((u >> 16) & 1u);
  h = (u16)(r >> 16);
  float fh = __uint_as_float(((unsigned)h) << 16);
  float res = v - fh;
  unsigned u2 = __float_as_uint(res);
  unsigned r2 = u2 + 0x7FFFu + ((u2 >> 16) & 1u);
  l = (u16)(r2 >> 16);
}

__device__ __forceinline__ u16 bf16r(float v) {
  unsigned u = __float_as_uint(v);
  return (u16)((u + 0x7FFFu + ((u >> 16) & 1u)) >> 16);
}
__device__ __forceinline__ float bf2f(u16 h) {
  return __uint_as_float(((unsigned)h) << 16);
}

// ------------- scan p1; MODE 0 also zeroes counts/pooled/nact + builds mask ------
template <int MODE>
__global__ __launch_bounds__(256) void scan_p1(const int* __restrict__ in,
                                               int* __restrict__ blocksum,
                                               float* __restrict__ dinv,
                                               int* __restrict__ counts,
                                               float* __restrict__ pooled,
                                               int* __restrict__ nact,
                                               u64* __restrict__ maskw, int N) {
  __shared__ int wsum[4];
  if (MODE == 0) {
    int gi = blockIdx.x * blockDim.x + threadIdx.x;
    int gstride = gridDim.x * blockDim.x;  // multiple of 64
    for (int j = gi; j < N; j += gstride) {
      counts[j] = 0;
      u64 m = __ballot(in[j] == 0);
      if ((threadIdx.x & 63) == 0) maskw[j >> 6] = m;
    }
    if (gi < F3) pooled[gi] = 0.0f;
    if (gi == 0) *nact = 0;
  }
  int base = blockIdx.x * 1024 + threadIdx.x * 4;
  int s = 0;
#pragma unroll
  for (int j = 0; j < 4; ++j) {
    int i = base + j;
    if (i < N) {
      int v = in[i];
      if (MODE == 0) s += (v == 0 ? 1 : 0);
      else {
        s += v;
        dinv[i] = rsqrtf(1.0f + (float)v);
      }
    }
  }
#pragma unroll
  for (int off = 32; off; off >>= 1) s += __shfl_xor(s, off);
  if ((threadIdx.x & 63) == 0) wsum[threadIdx.x >> 6] = s;
  __syncthreads();
  if (threadIdx.x == 0)
    blocksum[blockIdx.x] = wsum[0] + wsum[1] + wsum[2] + wsum[3];
}

// p3 computes its own block offset from raw blocksum (G <= 64 blocks, cheap).
template <int MODE>
__global__ __launch_bounds__(256) void scan_p3(const int* __restrict__ in,
                                               const int* __restrict__ blocksum,
                                               int* __restrict__ out0,
                                               int* __restrict__ out1,
                                               int* __restrict__ NmInt,
                                               float* __restrict__ mcnt, int N) {
  __shared__ int wsum[4];
  const int tid = threadIdx.x;
  int base = blockIdx.x * 1024 + tid * 4;
  int c[4];
  int tsum = 0;
#pragma unroll
  for (int j = 0; j < 4; ++j) {
    int i = base + j;
    c[j] = (i < N) ? ((MODE == 0) ? (in[i] == 0 ? 1 : 0) : in[i]) : 0;
    tsum += c[j];
  }
  int v = tsum;
#pragma unroll
  for (int off = 1; off < 64; off <<= 1) {
    int t = __shfl_up(v, off);
    if ((tid & 63) >= off) v += t;
  }
  int wexcl = v - tsum;
  if ((tid & 63) == 63) wsum[tid >> 6] = v;
  __shared__ int boff;
  if (tid == 0) {
    int b = 0;
    for (int j = 0; j < blockIdx.x; ++j) b += blocksum[j];
    boff = b;
  }
  __syncthreads();
  int wbase = 0;
  int wv = tid >> 6;
#pragma unroll
  for (int j = 0; j < 4; ++j)
    if (j < wv) wbase += wsum[j];
  int off0 = boff + wbase + wexcl;
#pragma unroll
  for (int j = 0; j < 4; ++j) {
    int i = base + j;
    if (i < N) {
      if (MODE == 0) {
        out0[i] = off0;
        if (c[j]) out1[off0] = i;
        off0 += c[j];
        if (i == N - 1) { *NmInt = off0; *mcnt = (float)off0; }
      } else {
        out0[i] = off0;
        out1[i] = off0;
        off0 += c[j];
        if (i == N - 1) out0[N] = off0;
      }
    }
  }
}

// ---- single full-edge scan using L1-resident bitmask; 1 atomic/block append ----
__global__ __launch_bounds__(256) void compact_edges_kernel(
    const int* __restrict__ ei, const u64* __restrict__ maskw,
    const int* __restrict__ newidx, int* __restrict__ nact,
    int2* __restrict__ ae, int* __restrict__ counts, int E) {
  __shared__ int wbase[4];
  const int tid = threadIdx.x;
  const int lane = tid & 63, wv = tid >> 6;
  const int e0 = blockIdx.x * 1024;
  int s[4], d[4];
  bool act[4];
  int cnt = 0;
#pragma unroll
  for (int j = 0; j < 4; ++j) {
    int e = e0 + j * 256 + tid;
    if (e < E) {
      s[j] = ei[e];
      d[j] = ei[E + e];
      bool bs = (maskw[s[j] >> 6] >> (s[j] & 63)) & 1ULL;
      bool bd = (maskw[d[j] >> 6] >> (d[j] & 63)) & 1ULL;
      act[j] = bs && bd;
    } else {
      act[j] = false;
    }
    cnt += act[j] ? 1 : 0;
  }
  int v = cnt;
#pragma unroll
  for (int off = 1; off < 64; off <<= 1) {
    int t = __shfl_up(v, off);
    if (lane >= off) v += t;
  }
  int wexcl = v - cnt;
  if (lane == 63) wbase[wv] = v;
  __syncthreads();
  if (tid == 0) {
    int t0 = wbase[0], t1 = wbase[1], t2 = wbase[2], t3 = wbase[3];
    int b = atomicAdd(nact, t0 + t1 + t2 + t3);
    wbase[0] = b;
    wbase[1] = b + t0;
    wbase[2] = b + t0 + t1;
    wbase[3] = b + t0 + t1 + t2;
  }
  __syncthreads();
  int pos = wbase[wv] + wexcl;
#pragma unroll
  for (int j = 0; j < 4; ++j) {
    if (act[j]) {
      int ns = newidx[s[j]], nd = newidx[d[j]];
      ae[pos] = make_int2(ns, nd);
      atomicAdd(&counts[nd], 1);
      ++pos;
    }
  }
}

// ---- CSR fill over active list ----
__global__ __launch_bounds__(256) void fill2_kernel(const int2* __restrict__ ae,
                                                    const int* __restrict__ nactp,
                                                    const float* __restrict__ dinv,
                                                    int* __restrict__ fill,
                                                    int* __restrict__ csr_src,
                                                    float* __restrict__ csr_w) {
  int n = *nactp;
  int i = blockIdx.x * blockDim.x + threadIdx.x;
  int stride = gridDim.x * blockDim.x;
  for (int e = i; e < n; e += stride) {
    int2 p = ae[e];
    int pos = atomicAdd(&fill[p.y], 1);
    csr_src[pos] = p.x;
    csr_w[pos] = dinv[p.x] * dinv[p.y];
  }
}

// ---- prep: weight splits (blocks 0..543) + z0c bf16 compacted emb (rest) ----
__global__ __launch_bounds__(256) void prep_kernel(
    const float* __restrict__ W1, const float* __restrict__ W2,
    const float* __restrict__ W3, const float* __restrict__ Wh1t,
    u16* __restrict__ T1h, u16* __restrict__ T1l,
    u16* __restrict__ T2h, u16* __restrict__ T2l,
    u16* __restrict__ T3h, u16* __restrict__ T3l,
    u16* __restrict__ Hh, u16* __restrict__ Hl,
    const int* __restrict__ nodelist, const float* __restrict__ emb,
    u16* __restrict__ z0c, const int* __restrict__ NmPtr) {
  const int WB = 544;  // 139264 / 256
  if (blockIdx.x < WB) {
    int i = blockIdx.x * 256 + threadIdx.x;
    const float* W; u16 *Th, *Tl; int FIN, FOUT, idx;
    if (i < 16384) { W = W1; Th = T1h; Tl = T1l; FIN = 64; FOUT = 256; idx = i; }
    else if (i < 81920) { W = W2; Th = T2h; Tl = T2l; FIN = 256; FOUT = 256; idx = i - 16384; }
    else if (i < 131072) { W = W3; Th = T3h; Tl = T3l; FIN = 256; FOUT = 192; idx = i - 81920; }
    else if (i < 139264) { W = Wh1t; Th = Hh; Tl = Hl; FIN = 64; FOUT = 128; idx = i - 131072; }
    else return;
    int k = idx / FOUT, c = idx % FOUT;
    u16 h, l;
    split2(W[idx], h, l);
    Th[(size_t)c * FIN + k] = h;
    Tl[(size_t)c * FIN + k] = l;
  } else {
    int Nm = *NmPtr;
    int i = (blockIdx.x - WB) * 256 + threadIdx.x;
    int stride = (gridDim.x - WB) * 256;
    int total = Nm * (HDIM / 4);
    for (int j = i; j < total; j += stride) {
      int row = j >> 4;
      int c = (j & 15) * 4;
      int xr = nodelist[row];
      float4 v = *(const float4*)&emb[(size_t)xr * HDIM + c];
      uint2v o;
      o[0] = (unsigned)bf16r(v.x) | ((unsigned)bf16r(v.y) << 16);
      o[1] = (unsigned)bf16r(v.z) | ((unsigned)bf16r(v.w) << 16);
      *(uint2v*)&z0c[(size_t)row * HDIM + c] = o;
    }
  }
}

// ---- input-side aggregation, 64-dim bf16 ----
__global__ __launch_bounds__(256) void agg64_kernel(
    const u16* __restrict__ z0c, const int* __restrict__ rowstart,
    const int* __restrict__ csr_src, const float* __restrict__ csr_w,
    const float* __restrict__ dinv,
    u16* __restrict__ Ab, const int* __restrict__ NmPtr) {
  const int Nm = *NmPtr;
  const int lane = threadIdx.x & 63;
  const int wid = (int)((blockIdx.x * blockDim.x + threadIdx.x) >> 6);
  const int nw = (int)((gridDim.x * blockDim.x) >> 6);
  for (int r = wid; r < Nm; r += nw) {
    const int e0 = rowstart[r];
    const int e1 = rowstart[r + 1];
    float di = dinv[r];
    float acc = di * di * bf2f(z0c[(size_t)r * HDIM + lane]);
    for (int eb = e0; eb < e1; eb += 8) {
      int s[8]; float w[8];
#pragma unroll
      for (int u = 0; u < 8; ++u) {
        int idx = eb + u;
        bool ok = idx < e1;
        s[u] = ok ? csr_src[idx] : r;
        w[u] = ok ? csr_w[idx] : 0.f;
      }
      float v[8];
#pragma unroll
      for (int u = 0; u < 8; ++u) v[u] = bf2f(z0c[(size_t)s[u] * HDIM + lane]);
#pragma unroll
      for (int u = 0; u < 8; ++u) acc += w[u] * v[u];
    }
    Ab[(size_t)r * HDIM + lane] = bf16r(acc);
  }
}

// ---- input-side aggregation, 256-dim bf16 ----
__global__ __launch_bounds__(256) void agg256_kernel(
    const u16* __restrict__ Z, const int* __restrict__ rowstart,
    const int* __restrict__ csr_src, const float* __restrict__ csr_w,
    const float* __restrict__ dinv,
    u16* __restrict__ Ab, const int* __restrict__ NmPtr) {
  const int Nm = *NmPtr;
  const int lane = threadIdx.x & 63;
  const int wid = (int)((blockIdx.x * blockDim.x + threadIdx.x) >> 6);
  const int nw = (int)((gridDim.x * blockDim.x) >> 6);
  for (int r = wid; r < Nm; r += nw) {
    const int e0 = rowstart[r];
    const int e1 = rowstart[r + 1];
    float di = dinv[r];
    float sn = di * di;
    uint2v sp = *(const uint2v*)&Z[(size_t)r * F1 + 4 * lane];
    float a0 = sn * __uint_as_float(sp[0] << 16);
    float a1 = sn * __uint_as_float(sp[0] & 0xFFFF0000u);
    float a2 = sn * __uint_as_float(sp[1] << 16);
    float a3 = sn * __uint_as_float(sp[1] & 0xFFFF0000u);
    for (int eb = e0; eb < e1; eb += 8) {
      int s[8]; float w[8];
#pragma unroll
      for (int u = 0; u < 8; ++u) {
        int idx = eb + u;
        bool ok = idx < e1;
        s[u] = ok ? csr_src[idx] : r;
        w[u] = ok ? csr_w[idx] : 0.f;
      }
      uint2v pv[8];
#pragma unroll
      for (int u = 0; u < 8; ++u) pv[u] = *(const uint2v*)&Z[(size_t)s[u] * F1 + 4 * lane];
#pragma unroll
      for (int u = 0; u < 8; ++u) {
        a0 += w[u] * __uint_as_float(pv[u][0] << 16);
        a1 += w[u] * __uint_as_float(pv[u][0] & 0xFFFF0000u);
        a2 += w[u] * __uint_as_float(pv[u][1] << 16);
        a3 += w[u] * __uint_as_float(pv[u][1] & 0xFFFF0000u);
      }
    }
    uint2v o;
    o[0] = (unsigned)bf16r(a0) | ((unsigned)bf16r(a1) << 16);
    o[1] = (unsigned)bf16r(a2) | ((unsigned)bf16r(a3) << 16);
    *(uint2v*)&Ab[(size_t)r * F1 + 4 * lane] = o;
  }
}

// ------- MFMA GEMM: A single bf16, W split hi/lo. 128-row tiles, COLS 128/192.
// MODE 1: Out(u16) = bf16(relu(acc+bias)).  MODE 2: pooled += sum_rows relu(acc+bias).
template <int FIN, int FOUT, int COLS, int MODE>
__global__ __launch_bounds__(256) void gemm_kernel(const u16* __restrict__ A,
                                                   const u16* __restrict__ Wh,
                                                   const u16* __restrict__ Wl,
                                                   const float* __restrict__ bias,
                                                   u16* __restrict__ Out,
                                                   float* __restrict__ pooled,
                                                   const int* __restrict__ NmPtr) {
  const int NI = COLS / 16;
  const int Nm = *NmPtr;
  const int r0 = blockIdx.x * 128, c0 = blockIdx.y * COLS;
  if (r0 >= Nm) return;
  __shared__ u16 AH[8 * 128 * 8];
  __shared__ u16 WH[8 * COLS * 8], WL[8 * COLS * 8];
  const int tid = threadIdx.x;
  const int lane = tid & 63, w = tid >> 6;
  const int l15 = lane & 15, l4 = lane >> 4;
  f32x4 acc[2][NI] = {};

  for (int k0 = 0; k0 < FIN; k0 += 64) {
#pragma unroll
    for (int p = 0; p < 4; ++p) {
      int e = p * 2048 + tid * 8;
      int r = e >> 6, ke = e & 63;
      int g0 = ke >> 2;
      int h = (g0 >> 2) & 1;
      int gp = (g0 & 3) | ((g0 >> 3) << 2);
      uint2v v0 = {0, 0}, v1 = {0, 0};
      if (r0 + r < Nm) {
        size_t gbase = (size_t)(r0 + r) * FIN + k0 + ke;
        v0 = *(const uint2v*)&A[gbase];
        v1 = *(const uint2v*)&A[gbase + 4];
      }
      *(uint2v*)&AH[((gp * 128 + r) * 8) + h * 4] = v0;
      *(uint2v*)&AH[(((gp + 1) * 128 + r) * 8) + h * 4] = v1;
    }
#pragma unroll
    for (int p = 0; p < COLS / 32; ++p) {
      int e = p * 2048 + tid * 8;
      int c = e >> 6, ke = e & 63;
      int g0 = ke >> 2;
      int h = (g0 >> 2) & 1;
      int gp = (g0 & 3) | ((g0 >> 3) << 2);
      size_t gbase = (size_t)(c0 + c) * FIN + k0 + ke;
      uint2v vh0 = *(const uint2v*)&Wh[gbase];
      uint2v vh1 = *(const uint2v*)&Wh[gbase + 4];
      uint2v vl0 = *(const uint2v*)&Wl[gbase];
      uint2v vl1 = *(const uint2v*)&Wl[gbase + 4];
      *(uint2v*)&WH[((gp * COLS + c) * 8) + h * 4] = vh0;
      *(uint2v*)&WH[(((gp + 1) * COLS + c) * 8) + h * 4] = vh1;
      *(uint2v*)&WL[((gp * COLS + c) * 8) + h * 4] = vl0;
      *(uint2v*)&WL[(((gp + 1) * COLS + c) * 8) + h * 4] = vl1;
    }
    __syncthreads();
#pragma unroll
    for (int ko = 0; ko < 2; ++ko) {
      const int gb = ko * 4 + l4;
      short8 af[2];
#pragma unroll
      for (int mi = 0; mi < 2; ++mi)
        af[mi] = *(const short8*)&AH[(gb * 128 + (w * 32 + mi * 16 + l15)) * 8];
#pragma unroll
      for (int ni = 0; ni < NI; ++ni) {
        int slot = gb * COLS + (ni * 16 + l15);
        short8 wh = *(const short8*)&WH[slot * 8];
        short8 wl = *(const short8*)&WL[slot * 8];
#pragma unroll
        for (int mi = 0; mi < 2; ++mi) {
          acc[mi][ni] = __builtin_amdgcn_mfma_f32_16x16x32_bf16(af[mi], wh, acc[mi][ni], 0, 0, 0);
          acc[mi][ni] = __builtin_amdgcn_mfma_f32_16x16x32_bf16(af[mi], wl, acc[mi][ni], 0, 0, 0);
        }
      }
    }
    __syncthreads();
  }

  float bb[NI];
#pragma unroll
  for (int ni = 0; ni < NI; ++ni) bb[ni] = bias[c0 + ni * 16 + l15];

  if (MODE == 1) {
#pragma unroll
    for (int mi = 0; mi < 2; ++mi)
#pragma unroll
      for (int ni = 0; ni < NI; ++ni)
#pragma unroll
        for (int j = 0; j < 4; ++j) {
          int row = r0 + w * 32 + mi * 16 + l4 * 4 + j;
          if (row < Nm)
            Out[(size_t)row * FOUT + c0 + ni * 16 + l15] =
                bf16r(fmaxf(acc[mi][ni][j] + bb[ni], 0.f));
        }
  } else {
    __shared__ float wred[4][COLS];
    float part[NI];
#pragma unroll
    for (int ni = 0; ni < NI; ++ni) part[ni] = 0.f;
#pragma unroll
    for (int mi = 0; mi < 2; ++mi)
#pragma unroll
      for (int ni = 0; ni < NI; ++ni)
#pragma unroll
        for (int j = 0; j < 4; ++j) {
          int row = r0 + w * 32 + mi * 16 + l4 * 4 + j;
          if (row < Nm) part[ni] += fmaxf(acc[mi][ni][j] + bb[ni], 0.f);
        }
#pragma unroll
    for (int ni = 0; ni < NI; ++ni) {
      part[ni] += __shfl_xor(part[ni], 16);
      part[ni] += __shfl_xor(part[ni], 32);
    }
    if (l4 == 0)
#pragma unroll
      for (int ni = 0; ni < NI; ++ni) wred[w][ni * 16 + l15] = part[ni];
    __syncthreads();
    if (tid < COLS) {
      float s = wred[0][tid] + wred[1][tid] + wred[2][tid] + wred[3][tid];
      atomicAdd(&pooled[c0 + tid], s);
    }
  }
}

// ---- MFMA head, 128-row tiles, fused phead/gw/hcst prologue ----
__global__ __launch_bounds__(256) void head_mfma_kernel(
    const int* __restrict__ x, const float* __restrict__ emb,
    const u16* __restrict__ Hh, const u16* __restrict__ Hl,
    const float* __restrict__ pooled, const float* __restrict__ mcnt,
    const float* __restrict__ Wh1, const float* __restrict__ bh1,
    const float* __restrict__ gamma, const float* __restrict__ beta,
    const float* __restrict__ Wh2, const float* __restrict__ bh2,
    float* __restrict__ out, int N) {
  const int tid = threadIdx.x;
  const int lane = tid & 63, w = tid >> 6;
  const int l15 = lane & 15, l4 = lane >> 4;
  const int r0 = blockIdx.x * 128;

  __shared__ float sph[FH], sgw[FH];
  __shared__ float shc;
  if (tid < FH) {
    float inv = 1.0f / *mcnt;
    float acc = bh1[tid];
    for (int k = 0; k < F3; ++k) acc += pooled[k] * inv * Wh1[k * FH + tid];
    sph[tid] = acc;
    const float bninv = 1.0f / sqrtf(1.0f + 1e-5f);
    sgw[tid] = gamma[tid] * bninv * Wh2[tid];
  }
  if (tid == 0) {
    float s = bh2[0];
    for (int i = 0; i < FH; ++i) s += beta[i] * Wh2[i];
    shc = s;
  }
  __syncthreads();

  f32x4 acc[2][8] = {};
  const short8 zfrag = {};

#pragma unroll
  for (int ko = 0; ko < 2; ++ko) {
    const int kb = 32 * ko + 4 * l4;
    short8 bh[8], bl[8], ah[2], al[2];
#pragma unroll
    for (int ni = 0; ni < 8; ++ni) {
      int col = ni * 16 + l15;
      const u16* p = &Hh[col * 64 + kb];
      ((uint2v*)&bh[ni])[0] = *(const uint2v*)p;
      ((uint2v*)&bh[ni])[1] = *(const uint2v*)(p + 16);
      const u16* q = &Hl[col * 64 + kb];
      ((uint2v*)&bl[ni])[0] = *(const uint2v*)q;
      ((uint2v*)&bl[ni])[1] = *(const uint2v*)(q + 16);
    }
#pragma unroll
    for (int mi = 0; mi < 2; ++mi) {
      int row = r0 + w * 32 + mi * 16 + l15;
      if (row < N) {
        int xr = x[row];
        const float* pr = &emb[(size_t)xr * HDIM + kb];
        float4 f0 = *(const float4*)pr;
        float4 f1 = *(const float4*)(pr + 16);
        u16 hh[8], ll[8];
        split2(f0.x, hh[0], ll[0]); split2(f0.y, hh[1], ll[1]);
        split2(f0.z, hh[2], ll[2]); split2(f0.w, hh[3], ll[3]);
        split2(f1.x, hh[4], ll[4]); split2(f1.y, hh[5], ll[5]);
        split2(f1.z, hh[6], ll[6]); split2(f1.w, hh[7], ll[7]);
        short8 a, b;
#pragma unroll
        for (int j = 0; j < 8; ++j) { a[j] = (short)hh[j]; b[j] = (short)ll[j]; }
        ah[mi] = a;
        al[mi] = b;
      } else {
        ah[mi] = zfrag;
        al[mi] = zfrag;
      }
    }
#pragma unroll
    for (int mi = 0; mi < 2; ++mi)
#pragma unroll
      for (int ni = 0; ni < 8; ++ni) {
        acc[mi][ni] = __builtin_amdgcn_mfma_f32_16x16x32_bf16(ah[mi], bh[ni], acc[mi][ni], 0, 0, 0);
        acc[mi][ni] = __builtin_amdgcn_mfma_f32_16x16x32_bf16(ah[mi], bl[ni], acc[mi][ni], 0, 0, 0);
        acc[mi][ni] = __builtin_amdgcn_mfma_f32_16x16x32_bf16(al[mi], bh[ni], acc[mi][ni], 0, 0, 0);
      }
  }

  const float hc = shc;
  float ph[8], g[8];
#pragma unroll
  for (int ni = 0; ni < 8; ++ni) {
    int col = ni * 16 + l15;
    ph[ni] = sph[col];
    g[ni] = sgw[col];
  }
#pragma unroll
  for (int mi = 0; mi < 2; ++mi)
#pragma unroll
    for (int j = 0; j < 4; ++j) {
      float s = 0.f;
#pragma unroll
      for (int ni = 0; ni < 8; ++ni)
        s += fmaxf(acc[mi][ni][j] + ph[ni], 0.f) * g[ni];
#pragma unroll
      for (int off = 1; off < 16; off <<= 1) s += __shfl_xor(s, off);
      int row = r0 + w * 32 + mi * 16 + l4 * 4 + j;
      if (l15 == 0 && row < N) out[row] = s + hc;
    }
}

extern "C" void kernel_launch(void* const* d_in, const int* in_sizes, int n_in,
                              void* d_out, int out_size, void* d_ws, size_t ws_size,
                              hipStream_t stream) {
  const int N = in_sizes[0];
  const int E = in_sizes[1] / 2;

  const int* x = (const int*)d_in[0];
  const int* ei = (const int*)d_in[1];
  const int* nt = (const int*)d_in[2];
  const float* emb = (const float*)d_in[3];
  const float* W1 = (const float*)d_in[4];
  const float* b1 = (const float*)d_in[5];
  const float* W2 = (const float*)d_in[6];
  const float* b2 = (const float*)d_in[7];
  const float* W3 = (const float*)d_in[8];
  const float* b3 = (const float*)d_in[9];
  const float* Wh1 = (const float*)d_in[10];
  const float* bh1 = (const float*)d_in[11];
  const float* gamma = (const float*)d_in[12];
  const float* beta = (const float*)d_in[13];
  const float* Wh2 = (const float*)d_in[14];
  const float* bh2 = (const float*)d_in[15];
  float* out = (float*)d_out;

  // workspace layout (bf16 activations)
  u16* Ab = (u16*)d_ws;                            // N*256 u16
  u16* Bz = Ab + (size_t)N * 256;                  // N*256 u16
  u16* WTh = Bz + (size_t)N * 256;                 // 131072
  u16* WTl = WTh + 131072;                         // 131072
  u16* Hh = WTl + 131072;                          // 8192
  u16* Hl = Hh + 8192;                             // 8192
  u16* z0c = Hl + 8192;                            // N*64 u16
  float* dinv = (float*)(z0c + (size_t)N * HDIM);  // N
  float* csr_w = dinv + N;                         // E
  int* csr_src = (int*)(csr_w + E);                // E
  int2* ae = (int2*)(csr_src + E);                 // E int2
  int* counts = (int*)(ae + E);                    // N
  int* fill = counts + N;                          // N
  int* rowstart = fill + N;                        // N+1
  int* newidx = rowstart + N + 2;                  // N
  int* nodelist = newidx + N;                      // N
  int* blocksum = nodelist + N;                    // 256
  int* NmInt = blocksum + 256;                     // 1
  int* nact = NmInt + 1;                           // 1
  float* pooled = (float*)(nact + 1);              // 192
  float* mcnt = pooled + F3;                       // 1
  u64* maskw = (u64*)(((size_t)(mcnt + 1) + 7) & ~(size_t)7);  // ceil(N/64)+1 u64
  (void)ws_size; (void)n_in; (void)out_size;

  u16* W1Th = WTh,         * W1Tl = WTl;
  u16* W2Th = WTh + 16384, * W2Tl = WTl + 16384;
  u16* W3Th = WTh + 81920, * W3Tl = WTl + 81920;

  const int rowBlocks = (N + 127) / 128;
  const int aggBlocks = (N + 3) / 4;
  const int scanBlocks = (N + 1023) / 1024;
  const int edgeBlocks = (E + 1023) / 1024;

  // mask scan (+ zero counts/pooled/nact, build bitmask): newidx/nodelist/Nm/mcnt
  scan_p1<0><<<scanBlocks, 256, 0, stream>>>(nt, blocksum, nullptr, counts, pooled, nact, maskw, N);
  scan_p3<0><<<scanBlocks, 256, 0, stream>>>(nt, blocksum, newidx, nodelist, NmInt, mcnt, N);
  // single full-edge pass (bitmask activity test) -> active list + in-degree counts
  compact_edges_kernel<<<edgeBlocks, 256, 0, stream>>>(ei, maskw, newidx, nact, ae, counts, E);
  // counts scan (+dinv): rowstart/fill
  scan_p1<1><<<scanBlocks, 256, 0, stream>>>(counts, blocksum, dinv, nullptr, nullptr, nullptr, maskw, N);
  scan_p3<1><<<scanBlocks, 256, 0, stream>>>(counts, blocksum, rowstart, fill, NmInt, mcnt, N);
  fill2_kernel<<<512, 256, 0, stream>>>(ae, nact, dinv, fill, csr_src, csr_w);
  // weight splits + compacted bf16 emb in one launch
  prep_kernel<<<544 + 1024, 256, 0, stream>>>(
      W1, W2, W3, Wh1 + F3 * FH, W1Th, W1Tl, W2Th, W2Tl, W3Th, W3Tl, Hh, Hl,
      nodelist, emb, z0c, NmInt);

  // layer 1
  agg64_kernel<<<aggBlocks, 256, 0, stream>>>(z0c, rowstart, csr_src, csr_w, dinv, Ab, NmInt);
  gemm_kernel<HDIM, F1, 128, 1><<<dim3(rowBlocks, 2), 256, 0, stream>>>(
      Ab, W1Th, W1Tl, b1, Bz, nullptr, NmInt);

  // layer 2
  agg256_kernel<<<aggBlocks, 256, 0, stream>>>(Bz, rowstart, csr_src, csr_w, dinv, Ab, NmInt);
  gemm_kernel<F1, F1, 128, 1><<<dim3(rowBlocks, 2), 256, 0, stream>>>(
      Ab, W2Th, W2Tl, b2, Bz, nullptr, NmInt);

  // layer 3 (+ fused pool; z3 never stored)
  agg256_kernel<<<aggBlocks, 256, 0, stream>>>(Bz, rowstart, csr_src, csr_w, dinv, Ab, NmInt);
  gemm_kernel<F1, F3, 192, 2><<<dim3(rowBlocks, 1), 256, 0, stream>>>(
      Ab, W3Th, W3Tl, b3, nullptr, pooled, NmInt);

  // head (128-row tiles, fused prologue)
  head_mfma_kernel<<<rowBlocks, 256, 0, stream>>>(
      x, emb, Hh, Hl, pooled, mcnt, Wh1, bh1, gamma, beta, Wh2, bh2, out, N);
}